// Round 8
// baseline (6282.417 us; speedup 1.0000x reference)
//
#include <hip/hip_runtime.h>

// ---------------------------------------------------------------------------
// ParamMemAdam: hs features collapse to a 64-entry token table. 256
// independent sequential Adam scans (3069 steps). R8: FOUR scans per block
// (1024 thr, grid 64) -- each scan is the proven R4 merged-role 256-thread
// structure (R5's exact-tree dhp, R7's packed Adam). 4 waves/SIMD from 4
// independent scans fill each other's stalls (barrier drain, LDS latency,
// sqrt/rcp chains). Lockstep block barriers; per-scan arithmetic bit-exact
// to the R1/R3/R4/R5/R7 trajectory. tab moved to uniform global s_loads.
// ---------------------------------------------------------------------------

typedef float v2f __attribute__((ext_vector_type(2)));

__device__ __forceinline__ v2f mk2(float a, float b) { v2f r; r.x = a; r.y = b; return r; }

__device__ __forceinline__ v2f pk_fma(v2f a, v2f b, v2f c) {
  return __builtin_elementwise_fma(a, b, c);
}
__device__ __forceinline__ v2f pk_mul(v2f a, v2f b) { return a * b; }

template <int CTRL>
__device__ __forceinline__ float dpp_add(float x) {
  union { float f; int i; } u, r;
  u.f = x;
  r.i = __builtin_amdgcn_update_dpp(0, u.i, CTRL, 0xF, 0xF, true);
  return x + r.f;
}

// Bit-identical to R1's scalar update (for b1).
__device__ __forceinline__ void adam_upd(float& p, float& m1, float& m2,
                                         float g, float c2inv, float nls)
{
  m1 = fmaf(0.9f,  m1, 0.1f   * g);
  m2 = fmaf(0.999f, m2, 0.001f * (g * g));
  float den = __builtin_amdgcn_sqrtf(m2 * c2inv) + 1e-8f;
  p = fmaf(nls * m1, __builtin_amdgcn_rcpf(den), p);
}

// Packed pair update: per-half ops identical to the scalar sequence.
__device__ __forceinline__ void adam_upd2(v2f& p, v2f& m1, v2f& m2,
                                          v2f g, v2f c2inv2, v2f nls2)
{
  m1 = pk_fma(mk2(0.9f, 0.9f),   m1, pk_mul(mk2(0.1f, 0.1f),   g));
  m2 = pk_fma(mk2(0.999f, 0.999f), m2,
              pk_mul(mk2(0.001f, 0.001f), pk_mul(g, g)));
  v2f d2 = pk_mul(m2, c2inv2);
  v2f den = mk2(__builtin_amdgcn_sqrtf(d2.x) + 1e-8f,
                __builtin_amdgcn_sqrtf(d2.y) + 1e-8f);
  v2f rec = mk2(__builtin_amdgcn_rcpf(den.x), __builtin_amdgcn_rcpf(den.y));
  p = pk_fma(pk_mul(nls2, m1), rec, p);
}

// ---- prep: hs_table[v][j] = LN(e_v + FF(e_v)) for the 64 possible tokens ----
__global__ void prep_kernel(const float* __restrict__ emb,
                            const float* __restrict__ ffw1, const float* __restrict__ ffb1,
                            const float* __restrict__ ffw2, const float* __restrict__ ffb2,
                            const float* __restrict__ lng,  const float* __restrict__ lnb,
                            float* __restrict__ hs_out)
{
  const int v = blockIdx.x;
  const int t = threadIdx.x;  // 128 threads
  __shared__ float e[64];
  __shared__ float r[128];
  if (t < 64) e[t] = emb[v * 64 + t];
  __syncthreads();
  {
    float s = ffb1[t];
    const float* wrow = ffw1 + t * 64;
#pragma unroll 8
    for (int m = 0; m < 64; ++m) s = fmaf(wrow[m], e[m], s);
    r[t] = fmaxf(s, 0.f);
  }
  __syncthreads();
  if (t < 64) {
    float s = ffb2[t];
    const float* wrow = ffw2 + t * 128;
#pragma unroll 8
    for (int o = 0; o < 128; ++o) s = fmaf(wrow[o], r[o], s);
    float x = e[t] + s;
    float mu = x;
    for (int m = 1; m < 64; m <<= 1) mu += __shfl_xor(mu, m, 64);
    mu *= (1.f / 64.f);
    float dv = x - mu;
    float var = dv * dv;
    for (int m = 1; m < 64; m <<= 1) var += __shfl_xor(var, m, 64);
    var *= (1.f / 64.f);
    float hs = dv / sqrtf(var + 1e-5f);
    hs_out[v * 64 + t] = hs * lng[t] + lnb[t];
  }
}

// ---- per-step Adam scale table: EXACT op sequence of the R1 in-loop code ----
__global__ __launch_bounds__(64)
void table_kernel(float* __restrict__ tab)   // tab[2n] = nls, tab[2n+1] = c2inv
{
  if (threadIdx.x != 0) return;
  double pb1 = 1.0, pb2 = 1.0;
  for (int n = 0; n < 3069; ++n) {
    pb1 *= 0.9; pb2 *= 0.999;
    float c1inv = __builtin_amdgcn_rcpf((float)(1.0 - pb1));
    float c2inv = __builtin_amdgcn_rcpf((float)(1.0 - pb2));
    tab[2 * n]     = -0.05f * c1inv;
    tab[2 * n + 1] = c2inv;
  }
}

// ---- main scan: FOUR batch elements per block, merged-role 256 thr each ---
// Per scan, thread t: w1 row i1=t>>3 cols j0..j0+7 + b1[i1] (x8 replicated);
// w2 rows p0=2*i1,p0+1 cols c0..c0+3 + b2 pair (x8 replicated).
__global__ __launch_bounds__(1024)
void scan_kernel(const int* __restrict__ seq, const float* __restrict__ hs_tab,
                 const float* __restrict__ tab_g,
                 const float* __restrict__ fc1w, const float* __restrict__ fc1b,
                 const float* __restrict__ fc2w, const float* __restrict__ fc2b,
                 const float* __restrict__ outw, const float* __restrict__ outb,
                 float* __restrict__ out)
{
  const int tid  = threadIdx.x;        // 0..1023
  const int sc   = tid >> 8;           // scan 0..3 within block
  const int t    = tid & 255;          // per-scan thread id (== R4's t)
  const int b    = blockIdx.x * 4 + sc;
  const int lane = t & 63;
  const int wv   = t >> 6;
  const int i1   = t >> 3;
  const int j0   = (t & 7) << 3;
  const int p0   = i1 << 1;
  const int c0   = (t & 7) << 2;
  const int sub  = t & 7;

  __shared__ __align__(16) float hs[4096];       // token table (shared by scans)
  __shared__ __align__(16) int   sq[4][2048];    // per-scan token ids
  __shared__ __align__(16) float h_s[4][32];     // per-scan hidden vector
  __shared__ __align__(16) float dhp[4][32][20]; // per-scan dh partials
  __shared__ __align__(16) float ctx[4][64];     // per-scan context

  ((float4*)hs)[tid] = ((const float4*)hs_tab)[tid];
  {
    const int4* sg = (const int4*)(seq + (long long)b * 2048);
    ((int4*)sq[sc])[t]       = sg[t];
    ((int4*)sq[sc])[t + 256] = sg[t + 256];
  }

  // ---- parameter state (merged role: every thread owns both layers' share)
  v2f w1p[4], m1a2[4], m2a2[4];
  float b1v, m1c = 0.f, m2c = 0.f;
  v2f w2p[4], m1b2[4], m2b2[4];
  v2f b2v2, m1d2 = mk2(0.f, 0.f), m2d2 = mk2(0.f, 0.f);
#pragma unroll
  for (int j = 0; j < 4; ++j) {
    m1a2[j] = mk2(0.f, 0.f); m2a2[j] = mk2(0.f, 0.f);
    m1b2[j] = mk2(0.f, 0.f); m2b2[j] = mk2(0.f, 0.f);
  }
  w2p[0] = mk2(fc2w[p0 * 32 + c0 + 0], fc2w[p0 * 32 + c0 + 1]);
  w2p[1] = mk2(fc2w[p0 * 32 + c0 + 2], fc2w[p0 * 32 + c0 + 3]);
  w2p[2] = mk2(fc2w[(p0 + 1) * 32 + c0 + 0], fc2w[(p0 + 1) * 32 + c0 + 1]);
  w2p[3] = mk2(fc2w[(p0 + 1) * 32 + c0 + 2], fc2w[(p0 + 1) * 32 + c0 + 3]);
  b2v2 = mk2(fc2b[p0], fc2b[p0 + 1]);
#pragma unroll
  for (int j = 0; j < 4; ++j)
    w1p[j] = mk2(fc1w[i1 * 64 + j0 + 2 * j], fc1w[i1 * 64 + j0 + 2 * j + 1]);
  b1v = fc1b[i1];

  __syncthreads();

  float nls_c = tab_g[0], c2i_c = tab_g[1];
  int jm = 1;
  float kk[8], hv, v0, v1;

  // ---- prologue: pair 0: A(0) -> h_s, v(0)
  {
    const int ka = sq[sc][0], vb = sq[sc][1];
    const float4 k0 = *(const float4*)(hs + ka * 64 + j0);
    const float4 k1 = *(const float4*)(hs + ka * 64 + j0 + 4);
    kk[0]=k0.x; kk[1]=k0.y; kk[2]=k0.z; kk[3]=k0.w;
    kk[4]=k1.x; kk[5]=k1.y; kk[6]=k1.z; kk[7]=k1.w;
    v0 = hs[vb * 64 + p0];
    v1 = hs[vb * 64 + p0 + 1];
    float pa = 0.f;
    pa = fmaf(w1p[0].x, kk[0], pa);
    pa = fmaf(w1p[0].y, kk[1], pa);
    pa = fmaf(w1p[1].x, kk[2], pa);
    pa = fmaf(w1p[1].y, kk[3], pa);
    pa = fmaf(w1p[2].x, kk[4], pa);
    pa = fmaf(w1p[2].y, kk[5], pa);
    pa = fmaf(w1p[3].x, kk[6], pa);
    pa = fmaf(w1p[3].y, kk[7], pa);
    pa = dpp_add<0xB1>(pa);   // xor1
    pa = dpp_add<0x4E>(pa);   // xor2
    pa = dpp_add<0x141>(pa);  // xor4-equiv (row_half_mirror)
    hv = fmaxf(pa + b1v, 0.f);
    if (sub == 1) h_s[sc][i1] = hv;
  }
  __syncthreads();

  for (int step = 0; step < 3069; ++step) {
    const float nls = nls_c, c2inv = c2i_c;
    {
      const int ni = (step < 3068) ? (step + 1) : 3068;
      nls_c = tab_g[2 * ni];         // uniform scalar loads, hidden 1 step
      c2i_c = tab_g[2 * ni + 1];
    }
    const v2f nls2 = mk2(nls, nls), c2inv2 = mk2(c2inv, c2inv);

    // ---- prefetch (k,v) for step+1 (query token on last step)
    float kn[8], v0n, v1n;
    {
      int ka, vb;
      if (step < 3068) {
        ka = sq[sc][2 * jm]; vb = sq[sc][2 * jm + 1];
        jm = (jm == 1022) ? 0 : jm + 1;
      } else {
        ka = sq[sc][2047]; vb = 0;
      }
      const float4 k0 = *(const float4*)(hs + ka * 64 + j0);
      const float4 k1 = *(const float4*)(hs + ka * 64 + j0 + 4);
      kn[0]=k0.x; kn[1]=k0.y; kn[2]=k0.z; kn[3]=k0.w;
      kn[4]=k1.x; kn[5]=k1.y; kn[6]=k1.z; kn[7]=k1.w;
      v0n = hs[vb * 64 + p0];
      v1n = hs[vb * 64 + p0 + 1];
    }

    // ---- B: pred = w2 h + b2 ; d = (2/64)(pred - v)
    const float4 h4 = *(const float4*)(&h_s[sc][c0]);
    const v2f hh0 = mk2(h4.x, h4.y), hh1 = mk2(h4.z, h4.w);
    float q0 = 0.f, q1 = 0.f;
    q0 = fmaf(w2p[0].x, hh0.x, q0);  q1 = fmaf(w2p[2].x, hh0.x, q1);
    q0 = fmaf(w2p[0].y, hh0.y, q0);  q1 = fmaf(w2p[2].y, hh0.y, q1);
    q0 = fmaf(w2p[1].x, hh1.x, q0);  q1 = fmaf(w2p[3].x, hh1.x, q1);
    q0 = fmaf(w2p[1].y, hh1.y, q0);  q1 = fmaf(w2p[3].y, hh1.y, q1);
    q0 = dpp_add<0xB1>(q0);   q1 = dpp_add<0xB1>(q1);
    q0 = dpp_add<0x4E>(q0);   q1 = dpp_add<0x4E>(q1);
    q0 = dpp_add<0x141>(q0);  q1 = dpp_add<0x141>(q1);
    const float dd0 = 0.03125f * (q0 + b2v2.x - v0);
    const float dd1 = 0.03125f * (q1 + b2v2.y - v1);

    // ---- C: dp partials with OLD w2; xor8; store 4 partials/col
    {
      float dp[4];
      dp[0] = fmaf(w2p[2].x, dd1, w2p[0].x * dd0);
      dp[1] = fmaf(w2p[2].y, dd1, w2p[0].y * dd0);
      dp[2] = fmaf(w2p[3].x, dd1, w2p[1].x * dd0);
      dp[3] = fmaf(w2p[3].y, dd1, w2p[1].y * dd0);
#pragma unroll
      for (int ii = 0; ii < 4; ++ii) dp[ii] = dpp_add<0x128>(dp[ii]);  // xor8
      if (!(lane & 8)) {
        const int slot = wv * 4 + (lane >> 4);
        const int colb = (lane & 7) << 2;
        dhp[sc][colb + 0][slot] = dp[0];
        dhp[sc][colb + 1][slot] = dp[1];
        dhp[sc][colb + 2][slot] = dp[2];
        dhp[sc][colb + 3][slot] = dp[3];
      }
    }

    // ---- w2/b2 Adam (dp captured old w2; updates independent)
    adam_upd2(w2p[0], m1b2[0], m2b2[0], pk_mul(mk2(dd0, dd0), hh0), c2inv2, nls2);
    adam_upd2(w2p[1], m1b2[1], m2b2[1], pk_mul(mk2(dd0, dd0), hh1), c2inv2, nls2);
    adam_upd2(w2p[2], m1b2[2], m2b2[2], pk_mul(mk2(dd1, dd1), hh0), c2inv2, nls2);
    adam_upd2(w2p[3], m1b2[3], m2b2[3], pk_mul(mk2(dd1, dd1), hh1), c2inv2, nls2);
    adam_upd2(b2v2, m1d2, m2d2, mk2(dd0, dd1), c2inv2, nls2);
    __syncthreads();

    // ---- D: dh from 16 partials, exact xor-tree order
    {
      const float4 pA = *(const float4*)&dhp[sc][i1][0];
      const float4 pB = *(const float4*)&dhp[sc][i1][4];
      const float4 pC = *(const float4*)&dhp[sc][i1][8];
      const float4 pD = *(const float4*)&dhp[sc][i1][12];
      const float W0 = (pA.x + pA.y) + (pA.z + pA.w);
      const float W1 = (pB.x + pB.y) + (pB.z + pB.w);
      const float W2 = (pC.x + pC.y) + (pC.z + pC.w);
      const float W3 = (pD.x + pD.y) + (pD.z + pD.w);
      const float dhsum = (W0 + W1) + (W2 + W3);
      const float dh = (hv > 0.f) ? dhsum : 0.f;
      const v2f dh2 = mk2(dh, dh);
      adam_upd2(w1p[0], m1a2[0], m2a2[0],
                pk_mul(dh2, mk2(kk[0], kk[1])), c2inv2, nls2);
      adam_upd2(w1p[1], m1a2[1], m2a2[1],
                pk_mul(dh2, mk2(kk[2], kk[3])), c2inv2, nls2);
      adam_upd2(w1p[2], m1a2[2], m2a2[2],
                pk_mul(dh2, mk2(kk[4], kk[5])), c2inv2, nls2);
      adam_upd2(w1p[3], m1a2[3], m2a2[3],
                pk_mul(dh2, mk2(kk[6], kk[7])), c2inv2, nls2);
      adam_upd(b1v, m1c, m2c, dh, c2inv, nls);
    }

    // ---- A: h(step+1) with updated w1 and prefetched k
    {
#pragma unroll
      for (int jj = 0; jj < 8; ++jj) kk[jj] = kn[jj];
      v0 = v0n; v1 = v1n;
      float pa = 0.f;
      pa = fmaf(w1p[0].x, kk[0], pa);
      pa = fmaf(w1p[0].y, kk[1], pa);
      pa = fmaf(w1p[1].x, kk[2], pa);
      pa = fmaf(w1p[1].y, kk[3], pa);
      pa = fmaf(w1p[2].x, kk[4], pa);
      pa = fmaf(w1p[2].y, kk[5], pa);
      pa = fmaf(w1p[3].x, kk[6], pa);
      pa = fmaf(w1p[3].y, kk[7], pa);
      pa = dpp_add<0xB1>(pa);
      pa = dpp_add<0x4E>(pa);
      pa = dpp_add<0x141>(pa);
      hv = fmaxf(pa + b1v, 0.f);
      if (sub == 1) h_s[sc][i1] = hv;
    }
    __syncthreads();
  }

  // ---- epilogue: ctx = w2 h_q + b2 (no relu on output layer)
  {
    const float4 h4 = *(const float4*)(&h_s[sc][c0]);
    float q0 = 0.f, q1 = 0.f;
    q0 = fmaf(w2p[0].x, h4.x, q0); q1 = fmaf(w2p[2].x, h4.x, q1);
    q0 = fmaf(w2p[0].y, h4.y, q0); q1 = fmaf(w2p[2].y, h4.y, q1);
    q0 = fmaf(w2p[1].x, h4.z, q0); q1 = fmaf(w2p[3].x, h4.z, q1);
    q0 = fmaf(w2p[1].y, h4.w, q0); q1 = fmaf(w2p[3].y, h4.w, q1);
    q0 = dpp_add<0xB1>(q0);   q1 = dpp_add<0xB1>(q1);
    q0 = dpp_add<0x4E>(q0);   q1 = dpp_add<0x4E>(q1);
    q0 = dpp_add<0x141>(q0);  q1 = dpp_add<0x141>(q1);
    if (sub == 2) { ctx[sc][p0] = q0 + b2v2.x; ctx[sc][p0 + 1] = q1 + b2v2.y; }
  }
  __syncthreads();

  // ---- output projection: out[b][u] = out_b[u] + sum_p out_w[u][p]*ctx[p]
  if (t < 64) {
    float acc = outb[t];
    const float* wrow = outw + t * 64;
#pragma unroll 8
    for (int p = 0; p < 64; ++p) acc = fmaf(wrow[p], ctx[sc][p], acc);
    out[(long long)b * 64 + t] = acc;
  }
}

extern "C" void kernel_launch(void* const* d_in, const int* in_sizes, int n_in,
                              void* d_out, int out_size, void* d_ws, size_t ws_size,
                              hipStream_t stream) {
  const int*   seq  = (const int*)  d_in[0];
  const float* emb  = (const float*)d_in[1];
  const float* ffw1 = (const float*)d_in[2];
  const float* ffb1 = (const float*)d_in[3];
  const float* ffw2 = (const float*)d_in[4];
  const float* ffb2 = (const float*)d_in[5];
  const float* lng  = (const float*)d_in[6];
  const float* lnb  = (const float*)d_in[7];
  const float* fc1w = (const float*)d_in[8];
  const float* fc1b = (const float*)d_in[9];
  const float* fc2w = (const float*)d_in[10];
  const float* fc2b = (const float*)d_in[11];
  const float* outw = (const float*)d_in[12];
  const float* outb = (const float*)d_in[13];
  float* out    = (float*)d_out;
  float* hs_tab = (float*)d_ws;            // 64*64 floats = 16 KB
  float* tab    = (float*)d_ws + 4096;     // 3069*2 floats

  prep_kernel<<<64, 128, 0, stream>>>(emb, ffw1, ffb1, ffw2, ffb2, lng, lnb, hs_tab);
  table_kernel<<<1, 64, 0, stream>>>(tab);
  scan_kernel<<<64, 1024, 0, stream>>>(seq, hs_tab, tab, fc1w, fc1b, fc2w, fc2b,
                                       outw, outb, out);
}

// Round 9
// 2460.892 us; speedup vs baseline: 2.5529x; 2.5529x over previous
//
#include <hip/hip_runtime.h>

// ---------------------------------------------------------------------------
// ParamMemAdam: hs features collapse to a 64-entry token table. 256
// independent sequential Adam scans (3069 steps) -> one block per batch
// element. R9 = best-known structure (merged-role 256 thr/scan, grid 256;
// R8's per-scan body = R4 DPP + R5 exact-tree dhp + R7 packed Adam, all
// proven bit-exact) + unroll-2 step loop (kills kk<-kn movs, widens the
// scheduling window across the barrier boundary) + uniform s_load tab.
// Trajectory bit-identical to R1/R3/R4/R5/R7/R8.
// ---------------------------------------------------------------------------

typedef float v2f __attribute__((ext_vector_type(2)));

__device__ __forceinline__ v2f mk2(float a, float b) { v2f r; r.x = a; r.y = b; return r; }

__device__ __forceinline__ v2f pk_fma(v2f a, v2f b, v2f c) {
  return __builtin_elementwise_fma(a, b, c);
}
__device__ __forceinline__ v2f pk_mul(v2f a, v2f b) { return a * b; }

template <int CTRL>
__device__ __forceinline__ float dpp_add(float x) {
  union { float f; int i; } u, r;
  u.f = x;
  r.i = __builtin_amdgcn_update_dpp(0, u.i, CTRL, 0xF, 0xF, true);
  return x + r.f;
}

// Bit-identical to R1's scalar update (for b1).
__device__ __forceinline__ void adam_upd(float& p, float& m1, float& m2,
                                         float g, float c2inv, float nls)
{
  m1 = fmaf(0.9f,  m1, 0.1f   * g);
  m2 = fmaf(0.999f, m2, 0.001f * (g * g));
  float den = __builtin_amdgcn_sqrtf(m2 * c2inv) + 1e-8f;
  p = fmaf(nls * m1, __builtin_amdgcn_rcpf(den), p);
}

// Packed pair update: per-half ops identical to the scalar sequence.
__device__ __forceinline__ void adam_upd2(v2f& p, v2f& m1, v2f& m2,
                                          v2f g, v2f c2inv2, v2f nls2)
{
  m1 = pk_fma(mk2(0.9f, 0.9f),   m1, pk_mul(mk2(0.1f, 0.1f),   g));
  m2 = pk_fma(mk2(0.999f, 0.999f), m2,
              pk_mul(mk2(0.001f, 0.001f), pk_mul(g, g)));
  v2f d2 = pk_mul(m2, c2inv2);
  v2f den = mk2(__builtin_amdgcn_sqrtf(d2.x) + 1e-8f,
                __builtin_amdgcn_sqrtf(d2.y) + 1e-8f);
  v2f rec = mk2(__builtin_amdgcn_rcpf(den.x), __builtin_amdgcn_rcpf(den.y));
  p = pk_fma(pk_mul(nls2, m1), rec, p);
}

// ---- prep: hs_table[v][j] = LN(e_v + FF(e_v)) for the 64 possible tokens ----
__global__ void prep_kernel(const float* __restrict__ emb,
                            const float* __restrict__ ffw1, const float* __restrict__ ffb1,
                            const float* __restrict__ ffw2, const float* __restrict__ ffb2,
                            const float* __restrict__ lng,  const float* __restrict__ lnb,
                            float* __restrict__ hs_out)
{
  const int v = blockIdx.x;
  const int t = threadIdx.x;  // 128 threads
  __shared__ float e[64];
  __shared__ float r[128];
  if (t < 64) e[t] = emb[v * 64 + t];
  __syncthreads();
  {
    float s = ffb1[t];
    const float* wrow = ffw1 + t * 64;
#pragma unroll 8
    for (int m = 0; m < 64; ++m) s = fmaf(wrow[m], e[m], s);
    r[t] = fmaxf(s, 0.f);
  }
  __syncthreads();
  if (t < 64) {
    float s = ffb2[t];
    const float* wrow = ffw2 + t * 128;
#pragma unroll 8
    for (int o = 0; o < 128; ++o) s = fmaf(wrow[o], r[o], s);
    float x = e[t] + s;
    float mu = x;
    for (int m = 1; m < 64; m <<= 1) mu += __shfl_xor(mu, m, 64);
    mu *= (1.f / 64.f);
    float dv = x - mu;
    float var = dv * dv;
    for (int m = 1; m < 64; m <<= 1) var += __shfl_xor(var, m, 64);
    var *= (1.f / 64.f);
    float hs = dv / sqrtf(var + 1e-5f);
    hs_out[v * 64 + t] = hs * lng[t] + lnb[t];
  }
}

// ---- per-step Adam scale table: EXACT op sequence of the R1 in-loop code ----
__global__ __launch_bounds__(64)
void table_kernel(float* __restrict__ tab)   // tab[2n] = nls, tab[2n+1] = c2inv
{
  if (threadIdx.x != 0) return;
  double pb1 = 1.0, pb2 = 1.0;
  for (int n = 0; n < 3069; ++n) {
    pb1 *= 0.9; pb2 *= 0.999;
    float c1inv = __builtin_amdgcn_rcpf((float)(1.0 - pb1));
    float c2inv = __builtin_amdgcn_rcpf((float)(1.0 - pb2));
    tab[2 * n]     = -0.05f * c1inv;
    tab[2 * n + 1] = c2inv;
  }
}

// ---- main scan: one batch element per block, merged-role 256 threads ------
// thread t: w1 row i1=t>>3 cols j0..j0+7 + b1[i1] (x8 replicated);
// w2 rows p0=2*i1,p0+1 cols c0..c0+3 + b2 pair (x8 replicated).
__global__ __launch_bounds__(256)
void scan_kernel(const int* __restrict__ seq, const float* __restrict__ hs_tab,
                 const float* __restrict__ tab_g,
                 const float* __restrict__ fc1w, const float* __restrict__ fc1b,
                 const float* __restrict__ fc2w, const float* __restrict__ fc2b,
                 const float* __restrict__ outw, const float* __restrict__ outb,
                 float* __restrict__ out)
{
  const int b    = blockIdx.x;
  const int t    = threadIdx.x;
  const int lane = t & 63;
  const int wv   = t >> 6;
  const int i1   = t >> 3;
  const int j0   = (t & 7) << 3;
  const int p0   = i1 << 1;
  const int c0   = (t & 7) << 2;
  const int sub  = t & 7;

  __shared__ __align__(16) float hs[4096];     // token table 64x64
  __shared__ __align__(16) int   sq[2048];     // token ids
  __shared__ __align__(16) float h_s[32];      // hidden vector
  __shared__ __align__(16) float dhp[32][20];  // dh partials [h-col][wv*4+q]
  __shared__ __align__(16) float ctx[64];      // final context

  for (int i = t; i < 1024; i += 256)
    ((float4*)hs)[i] = ((const float4*)hs_tab)[i];
  {
    const int4* sg = (const int4*)(seq + (long long)b * 2048);
    ((int4*)sq)[t]       = sg[t];
    ((int4*)sq)[t + 256] = sg[t + 256];
  }

  // ---- parameter state (merged role)
  v2f w1p[4], m1a2[4], m2a2[4];
  float b1v, m1c = 0.f, m2c = 0.f;
  v2f w2p[4], m1b2[4], m2b2[4];
  v2f b2v2, m1d2 = mk2(0.f, 0.f), m2d2 = mk2(0.f, 0.f);
#pragma unroll
  for (int j = 0; j < 4; ++j) {
    m1a2[j] = mk2(0.f, 0.f); m2a2[j] = mk2(0.f, 0.f);
    m1b2[j] = mk2(0.f, 0.f); m2b2[j] = mk2(0.f, 0.f);
  }
  w2p[0] = mk2(fc2w[p0 * 32 + c0 + 0], fc2w[p0 * 32 + c0 + 1]);
  w2p[1] = mk2(fc2w[p0 * 32 + c0 + 2], fc2w[p0 * 32 + c0 + 3]);
  w2p[2] = mk2(fc2w[(p0 + 1) * 32 + c0 + 0], fc2w[(p0 + 1) * 32 + c0 + 1]);
  w2p[3] = mk2(fc2w[(p0 + 1) * 32 + c0 + 2], fc2w[(p0 + 1) * 32 + c0 + 3]);
  b2v2 = mk2(fc2b[p0], fc2b[p0 + 1]);
#pragma unroll
  for (int j = 0; j < 4; ++j)
    w1p[j] = mk2(fc1w[i1 * 64 + j0 + 2 * j], fc1w[i1 * 64 + j0 + 2 * j + 1]);
  b1v = fc1b[i1];

  __syncthreads();

  float nls_c = tab_g[0], c2i_c = tab_g[1];
  int jm = 1;
  float kk[8], hv, v0, v1;

  // ---- prologue: pair 0: A(0) -> h_s, v(0)
  {
    const int ka = sq[0], vb = sq[1];
    const float4 k0 = *(const float4*)(hs + ka * 64 + j0);
    const float4 k1 = *(const float4*)(hs + ka * 64 + j0 + 4);
    kk[0]=k0.x; kk[1]=k0.y; kk[2]=k0.z; kk[3]=k0.w;
    kk[4]=k1.x; kk[5]=k1.y; kk[6]=k1.z; kk[7]=k1.w;
    v0 = hs[vb * 64 + p0];
    v1 = hs[vb * 64 + p0 + 1];
    float pa = 0.f;
    pa = fmaf(w1p[0].x, kk[0], pa);
    pa = fmaf(w1p[0].y, kk[1], pa);
    pa = fmaf(w1p[1].x, kk[2], pa);
    pa = fmaf(w1p[1].y, kk[3], pa);
    pa = fmaf(w1p[2].x, kk[4], pa);
    pa = fmaf(w1p[2].y, kk[5], pa);
    pa = fmaf(w1p[3].x, kk[6], pa);
    pa = fmaf(w1p[3].y, kk[7], pa);
    pa = dpp_add<0xB1>(pa);   // xor1
    pa = dpp_add<0x4E>(pa);   // xor2
    pa = dpp_add<0x141>(pa);  // xor4-equiv (row_half_mirror)
    hv = fmaxf(pa + b1v, 0.f);
    if (sub == 1) h_s[i1] = hv;
  }
  __syncthreads();

#pragma unroll 2
  for (int step = 0; step < 3069; ++step) {
    const float nls = nls_c, c2inv = c2i_c;
    {
      const int ni = (step < 3068) ? (step + 1) : 3068;
      nls_c = tab_g[2 * ni];         // uniform scalar loads, 1 step ahead
      c2i_c = tab_g[2 * ni + 1];
    }
    const v2f nls2 = mk2(nls, nls), c2inv2 = mk2(c2inv, c2inv);

    // ---- prefetch (k,v) for step+1 (query token on last step)
    float kn[8], v0n, v1n;
    {
      int ka, vb;
      if (step < 3068) {
        ka = sq[2 * jm]; vb = sq[2 * jm + 1];
        jm = (jm == 1022) ? 0 : jm + 1;
      } else {
        ka = sq[2047]; vb = 0;
      }
      const float4 k0 = *(const float4*)(hs + ka * 64 + j0);
      const float4 k1 = *(const float4*)(hs + ka * 64 + j0 + 4);
      kn[0]=k0.x; kn[1]=k0.y; kn[2]=k0.z; kn[3]=k0.w;
      kn[4]=k1.x; kn[5]=k1.y; kn[6]=k1.z; kn[7]=k1.w;
      v0n = hs[vb * 64 + p0];
      v1n = hs[vb * 64 + p0 + 1];
    }

    // ---- B: pred = w2 h + b2 ; d = (2/64)(pred - v)
    const float4 h4 = *(const float4*)(&h_s[c0]);
    const v2f hh0 = mk2(h4.x, h4.y), hh1 = mk2(h4.z, h4.w);
    float q0 = 0.f, q1 = 0.f;
    q0 = fmaf(w2p[0].x, hh0.x, q0);  q1 = fmaf(w2p[2].x, hh0.x, q1);
    q0 = fmaf(w2p[0].y, hh0.y, q0);  q1 = fmaf(w2p[2].y, hh0.y, q1);
    q0 = fmaf(w2p[1].x, hh1.x, q0);  q1 = fmaf(w2p[3].x, hh1.x, q1);
    q0 = fmaf(w2p[1].y, hh1.y, q0);  q1 = fmaf(w2p[3].y, hh1.y, q1);
    q0 = dpp_add<0xB1>(q0);   q1 = dpp_add<0xB1>(q1);
    q0 = dpp_add<0x4E>(q0);   q1 = dpp_add<0x4E>(q1);
    q0 = dpp_add<0x141>(q0);  q1 = dpp_add<0x141>(q1);
    const float dd0 = 0.03125f * (q0 + b2v2.x - v0);
    const float dd1 = 0.03125f * (q1 + b2v2.y - v1);

    // ---- C: dp partials with OLD w2; xor8; store 4 partials/col
    {
      float dp[4];
      dp[0] = fmaf(w2p[2].x, dd1, w2p[0].x * dd0);
      dp[1] = fmaf(w2p[2].y, dd1, w2p[0].y * dd0);
      dp[2] = fmaf(w2p[3].x, dd1, w2p[1].x * dd0);
      dp[3] = fmaf(w2p[3].y, dd1, w2p[1].y * dd0);
#pragma unroll
      for (int ii = 0; ii < 4; ++ii) dp[ii] = dpp_add<0x128>(dp[ii]);  // xor8
      if (!(lane & 8)) {
        const int slot = wv * 4 + (lane >> 4);
        const int colb = (lane & 7) << 2;
        dhp[colb + 0][slot] = dp[0];
        dhp[colb + 1][slot] = dp[1];
        dhp[colb + 2][slot] = dp[2];
        dhp[colb + 3][slot] = dp[3];
      }
    }

    // ---- w2/b2 Adam (dp captured old w2; updates independent)
    adam_upd2(w2p[0], m1b2[0], m2b2[0], pk_mul(mk2(dd0, dd0), hh0), c2inv2, nls2);
    adam_upd2(w2p[1], m1b2[1], m2b2[1], pk_mul(mk2(dd0, dd0), hh1), c2inv2, nls2);
    adam_upd2(w2p[2], m1b2[2], m2b2[2], pk_mul(mk2(dd1, dd1), hh0), c2inv2, nls2);
    adam_upd2(w2p[3], m1b2[3], m2b2[3], pk_mul(mk2(dd1, dd1), hh1), c2inv2, nls2);
    adam_upd2(b2v2, m1d2, m2d2, mk2(dd0, dd1), c2inv2, nls2);
    __syncthreads();

    // ---- D: dh from 16 partials, exact xor-tree order
    {
      const float4 pA = *(const float4*)&dhp[i1][0];
      const float4 pB = *(const float4*)&dhp[i1][4];
      const float4 pC = *(const float4*)&dhp[i1][8];
      const float4 pD = *(const float4*)&dhp[i1][12];
      const float W0 = (pA.x + pA.y) + (pA.z + pA.w);
      const float W1 = (pB.x + pB.y) + (pB.z + pB.w);
      const float W2 = (pC.x + pC.y) + (pC.z + pC.w);
      const float W3 = (pD.x + pD.y) + (pD.z + pD.w);
      const float dhsum = (W0 + W1) + (W2 + W3);
      const float dh = (hv > 0.f) ? dhsum : 0.f;
      const v2f dh2 = mk2(dh, dh);
      adam_upd2(w1p[0], m1a2[0], m2a2[0],
                pk_mul(dh2, mk2(kk[0], kk[1])), c2inv2, nls2);
      adam_upd2(w1p[1], m1a2[1], m2a2[1],
                pk_mul(dh2, mk2(kk[2], kk[3])), c2inv2, nls2);
      adam_upd2(w1p[2], m1a2[2], m2a2[2],
                pk_mul(dh2, mk2(kk[4], kk[5])), c2inv2, nls2);
      adam_upd2(w1p[3], m1a2[3], m2a2[3],
                pk_mul(dh2, mk2(kk[6], kk[7])), c2inv2, nls2);
      adam_upd(b1v, m1c, m2c, dh, c2inv, nls);
    }

    // ---- A: h(step+1) with updated w1 and prefetched k
    {
#pragma unroll
      for (int jj = 0; jj < 8; ++jj) kk[jj] = kn[jj];
      v0 = v0n; v1 = v1n;
      float pa = 0.f;
      pa = fmaf(w1p[0].x, kk[0], pa);
      pa = fmaf(w1p[0].y, kk[1], pa);
      pa = fmaf(w1p[1].x, kk[2], pa);
      pa = fmaf(w1p[1].y, kk[3], pa);
      pa = fmaf(w1p[2].x, kk[4], pa);
      pa = fmaf(w1p[2].y, kk[5], pa);
      pa = fmaf(w1p[3].x, kk[6], pa);
      pa = fmaf(w1p[3].y, kk[7], pa);
      pa = dpp_add<0xB1>(pa);
      pa = dpp_add<0x4E>(pa);
      pa = dpp_add<0x141>(pa);
      hv = fmaxf(pa + b1v, 0.f);
      if (sub == 1) h_s[i1] = hv;
    }
    __syncthreads();
  }

  // ---- epilogue: ctx = w2 h_q + b2 (no relu on output layer)
  {
    const float4 h4 = *(const float4*)(&h_s[c0]);
    float q0 = 0.f, q1 = 0.f;
    q0 = fmaf(w2p[0].x, h4.x, q0); q1 = fmaf(w2p[2].x, h4.x, q1);
    q0 = fmaf(w2p[0].y, h4.y, q0); q1 = fmaf(w2p[2].y, h4.y, q1);
    q0 = fmaf(w2p[1].x, h4.z, q0); q1 = fmaf(w2p[3].x, h4.z, q1);
    q0 = fmaf(w2p[1].y, h4.w, q0); q1 = fmaf(w2p[3].y, h4.w, q1);
    q0 = dpp_add<0xB1>(q0);   q1 = dpp_add<0xB1>(q1);
    q0 = dpp_add<0x4E>(q0);   q1 = dpp_add<0x4E>(q1);
    q0 = dpp_add<0x141>(q0);  q1 = dpp_add<0x141>(q1);
    if (sub == 2) { ctx[p0] = q0 + b2v2.x; ctx[p0 + 1] = q1 + b2v2.y; }
  }
  __syncthreads();

  // ---- output projection: out[b][u] = out_b[u] + sum_p out_w[u][p]*ctx[p]
  if (t < 64) {
    float acc = outb[t];
    const float* wrow = outw + t * 64;
#pragma unroll 8
    for (int p = 0; p < 64; ++p) acc = fmaf(wrow[p], ctx[p], acc);
    out[(long long)b * 64 + t] = acc;
  }
}

extern "C" void kernel_launch(void* const* d_in, const int* in_sizes, int n_in,
                              void* d_out, int out_size, void* d_ws, size_t ws_size,
                              hipStream_t stream) {
  const int*   seq  = (const int*)  d_in[0];
  const float* emb  = (const float*)d_in[1];
  const float* ffw1 = (const float*)d_in[2];
  const float* ffb1 = (const float*)d_in[3];
  const float* ffw2 = (const float*)d_in[4];
  const float* ffb2 = (const float*)d_in[5];
  const float* lng  = (const float*)d_in[6];
  const float* lnb  = (const float*)d_in[7];
  const float* fc1w = (const float*)d_in[8];
  const float* fc1b = (const float*)d_in[9];
  const float* fc2w = (const float*)d_in[10];
  const float* fc2b = (const float*)d_in[11];
  const float* outw = (const float*)d_in[12];
  const float* outb = (const float*)d_in[13];
  float* out    = (float*)d_out;
  float* hs_tab = (float*)d_ws;            // 64*64 floats = 16 KB
  float* tab    = (float*)d_ws + 4096;     // 3069*2 floats

  prep_kernel<<<64, 128, 0, stream>>>(emb, ffw1, ffb1, ffw2, ffb2, lng, lnb, hs_tab);
  table_kernel<<<1, 64, 0, stream>>>(tab);
  scan_kernel<<<256, 256, 0, stream>>>(seq, hs_tab, tab, fc1w, fc1b, fc2w, fc2b,
                                       outw, outb, out);
}

// Round 10
// 2344.317 us; speedup vs baseline: 2.6798x; 1.0497x over previous
//
#include <hip/hip_runtime.h>

// ---------------------------------------------------------------------------
// ParamMemAdam: hs features collapse to a 64-entry token table. 256
// independent sequential Adam scans (3069 steps) -> one block per batch
// element. R10 = R9 (merged-role 256 thr/scan, grid 256, packed Adam,
// exact-tree dhp, unroll) + LDS-order fix: the critical h4 read is issued
// FIRST in the loop body (LDS returns in-order; in R9 it sat behind the
// whole prefetch block, adding ~150-250cy to the critical path), prefetches
// drain under B/C/Adam. unroll 4. Trajectory bit-identical to R1..R9.
// ---------------------------------------------------------------------------

typedef float v2f __attribute__((ext_vector_type(2)));

__device__ __forceinline__ v2f mk2(float a, float b) { v2f r; r.x = a; r.y = b; return r; }

__device__ __forceinline__ v2f pk_fma(v2f a, v2f b, v2f c) {
  return __builtin_elementwise_fma(a, b, c);
}
__device__ __forceinline__ v2f pk_mul(v2f a, v2f b) { return a * b; }

template <int CTRL>
__device__ __forceinline__ float dpp_add(float x) {
  union { float f; int i; } u, r;
  u.f = x;
  r.i = __builtin_amdgcn_update_dpp(0, u.i, CTRL, 0xF, 0xF, true);
  return x + r.f;
}

// Bit-identical to R1's scalar update (for b1).
__device__ __forceinline__ void adam_upd(float& p, float& m1, float& m2,
                                         float g, float c2inv, float nls)
{
  m1 = fmaf(0.9f,  m1, 0.1f   * g);
  m2 = fmaf(0.999f, m2, 0.001f * (g * g));
  float den = __builtin_amdgcn_sqrtf(m2 * c2inv) + 1e-8f;
  p = fmaf(nls * m1, __builtin_amdgcn_rcpf(den), p);
}

// Packed pair update: per-half ops identical to the scalar sequence.
__device__ __forceinline__ void adam_upd2(v2f& p, v2f& m1, v2f& m2,
                                          v2f g, v2f c2inv2, v2f nls2)
{
  m1 = pk_fma(mk2(0.9f, 0.9f),   m1, pk_mul(mk2(0.1f, 0.1f),   g));
  m2 = pk_fma(mk2(0.999f, 0.999f), m2,
              pk_mul(mk2(0.001f, 0.001f), pk_mul(g, g)));
  v2f d2 = pk_mul(m2, c2inv2);
  v2f den = mk2(__builtin_amdgcn_sqrtf(d2.x) + 1e-8f,
                __builtin_amdgcn_sqrtf(d2.y) + 1e-8f);
  v2f rec = mk2(__builtin_amdgcn_rcpf(den.x), __builtin_amdgcn_rcpf(den.y));
  p = pk_fma(pk_mul(nls2, m1), rec, p);
}

// ---- prep: hs_table[v][j] = LN(e_v + FF(e_v)) for the 64 possible tokens ----
__global__ void prep_kernel(const float* __restrict__ emb,
                            const float* __restrict__ ffw1, const float* __restrict__ ffb1,
                            const float* __restrict__ ffw2, const float* __restrict__ ffb2,
                            const float* __restrict__ lng,  const float* __restrict__ lnb,
                            float* __restrict__ hs_out)
{
  const int v = blockIdx.x;
  const int t = threadIdx.x;  // 128 threads
  __shared__ float e[64];
  __shared__ float r[128];
  if (t < 64) e[t] = emb[v * 64 + t];
  __syncthreads();
  {
    float s = ffb1[t];
    const float* wrow = ffw1 + t * 64;
#pragma unroll 8
    for (int m = 0; m < 64; ++m) s = fmaf(wrow[m], e[m], s);
    r[t] = fmaxf(s, 0.f);
  }
  __syncthreads();
  if (t < 64) {
    float s = ffb2[t];
    const float* wrow = ffw2 + t * 128;
#pragma unroll 8
    for (int o = 0; o < 128; ++o) s = fmaf(wrow[o], r[o], s);
    float x = e[t] + s;
    float mu = x;
    for (int m = 1; m < 64; m <<= 1) mu += __shfl_xor(mu, m, 64);
    mu *= (1.f / 64.f);
    float dv = x - mu;
    float var = dv * dv;
    for (int m = 1; m < 64; m <<= 1) var += __shfl_xor(var, m, 64);
    var *= (1.f / 64.f);
    float hs = dv / sqrtf(var + 1e-5f);
    hs_out[v * 64 + t] = hs * lng[t] + lnb[t];
  }
}

// ---- per-step Adam scale table: EXACT op sequence of the R1 in-loop code ----
__global__ __launch_bounds__(64)
void table_kernel(float* __restrict__ tab)   // tab[2n] = nls, tab[2n+1] = c2inv
{
  if (threadIdx.x != 0) return;
  double pb1 = 1.0, pb2 = 1.0;
  for (int n = 0; n < 3069; ++n) {
    pb1 *= 0.9; pb2 *= 0.999;
    float c1inv = __builtin_amdgcn_rcpf((float)(1.0 - pb1));
    float c2inv = __builtin_amdgcn_rcpf((float)(1.0 - pb2));
    tab[2 * n]     = -0.05f * c1inv;
    tab[2 * n + 1] = c2inv;
  }
}

// ---- main scan: one batch element per block, merged-role 256 threads ------
__global__ __launch_bounds__(256)
void scan_kernel(const int* __restrict__ seq, const float* __restrict__ hs_tab,
                 const float* __restrict__ tab_g,
                 const float* __restrict__ fc1w, const float* __restrict__ fc1b,
                 const float* __restrict__ fc2w, const float* __restrict__ fc2b,
                 const float* __restrict__ outw, const float* __restrict__ outb,
                 float* __restrict__ out)
{
  const int b    = blockIdx.x;
  const int t    = threadIdx.x;
  const int lane = t & 63;
  const int wv   = t >> 6;
  const int i1   = t >> 3;
  const int j0   = (t & 7) << 3;
  const int p0   = i1 << 1;
  const int c0   = (t & 7) << 2;
  const int sub  = t & 7;

  __shared__ __align__(16) float hs[4096];     // token table 64x64
  __shared__ __align__(16) int   sq[2048];     // token ids
  __shared__ __align__(16) float h_s[32];      // hidden vector
  __shared__ __align__(16) float dhp[32][20];  // dh partials [h-col][wv*4+q]
  __shared__ __align__(16) float ctx[64];      // final context

  for (int i = t; i < 1024; i += 256)
    ((float4*)hs)[i] = ((const float4*)hs_tab)[i];
  {
    const int4* sg = (const int4*)(seq + (long long)b * 2048);
    ((int4*)sq)[t]       = sg[t];
    ((int4*)sq)[t + 256] = sg[t + 256];
  }

  // ---- parameter state (merged role)
  v2f w1p[4], m1a2[4], m2a2[4];
  float b1v, m1c = 0.f, m2c = 0.f;
  v2f w2p[4], m1b2[4], m2b2[4];
  v2f b2v2, m1d2 = mk2(0.f, 0.f), m2d2 = mk2(0.f, 0.f);
#pragma unroll
  for (int j = 0; j < 4; ++j) {
    m1a2[j] = mk2(0.f, 0.f); m2a2[j] = mk2(0.f, 0.f);
    m1b2[j] = mk2(0.f, 0.f); m2b2[j] = mk2(0.f, 0.f);
  }
  w2p[0] = mk2(fc2w[p0 * 32 + c0 + 0], fc2w[p0 * 32 + c0 + 1]);
  w2p[1] = mk2(fc2w[p0 * 32 + c0 + 2], fc2w[p0 * 32 + c0 + 3]);
  w2p[2] = mk2(fc2w[(p0 + 1) * 32 + c0 + 0], fc2w[(p0 + 1) * 32 + c0 + 1]);
  w2p[3] = mk2(fc2w[(p0 + 1) * 32 + c0 + 2], fc2w[(p0 + 1) * 32 + c0 + 3]);
  b2v2 = mk2(fc2b[p0], fc2b[p0 + 1]);
#pragma unroll
  for (int j = 0; j < 4; ++j)
    w1p[j] = mk2(fc1w[i1 * 64 + j0 + 2 * j], fc1w[i1 * 64 + j0 + 2 * j + 1]);
  b1v = fc1b[i1];

  __syncthreads();

  float nls_c = tab_g[0], c2i_c = tab_g[1];
  int jm = 1;
  float kk[8], hv, v0, v1;

  // ---- prologue: pair 0: A(0) -> h_s, v(0)
  {
    const int ka = sq[0], vb = sq[1];
    const float4 k0 = *(const float4*)(hs + ka * 64 + j0);
    const float4 k1 = *(const float4*)(hs + ka * 64 + j0 + 4);
    kk[0]=k0.x; kk[1]=k0.y; kk[2]=k0.z; kk[3]=k0.w;
    kk[4]=k1.x; kk[5]=k1.y; kk[6]=k1.z; kk[7]=k1.w;
    v0 = hs[vb * 64 + p0];
    v1 = hs[vb * 64 + p0 + 1];
    float pa = 0.f;
    pa = fmaf(w1p[0].x, kk[0], pa);
    pa = fmaf(w1p[0].y, kk[1], pa);
    pa = fmaf(w1p[1].x, kk[2], pa);
    pa = fmaf(w1p[1].y, kk[3], pa);
    pa = fmaf(w1p[2].x, kk[4], pa);
    pa = fmaf(w1p[2].y, kk[5], pa);
    pa = fmaf(w1p[3].x, kk[6], pa);
    pa = fmaf(w1p[3].y, kk[7], pa);
    pa = dpp_add<0xB1>(pa);   // xor1
    pa = dpp_add<0x4E>(pa);   // xor2
    pa = dpp_add<0x141>(pa);  // xor4-equiv (row_half_mirror)
    hv = fmaxf(pa + b1v, 0.f);
    if (sub == 1) h_s[i1] = hv;
  }
  __syncthreads();

#pragma unroll 4
  for (int step = 0; step < 3069; ++step) {
    // ---- CRITICAL READ FIRST: h4 (B's input) issues before anything else,
    //      so its lgkmcnt wait does not drain the prefetch block (LDS
    //      returns are in-order).
    const float4 h4 = *(const float4*)(&h_s[c0]);

    const float nls = nls_c, c2inv = c2i_c;
    const v2f nls2 = mk2(nls, nls), c2inv2 = mk2(c2inv, c2inv);

    // ---- prefetch (k,v) for step+1 (query token on last step)
    float kn[8], v0n, v1n;
    {
      int ka, vb;
      if (step < 3068) {
        ka = sq[2 * jm]; vb = sq[2 * jm + 1];
        jm = (jm == 1022) ? 0 : jm + 1;
      } else {
        ka = sq[2047]; vb = 0;
      }
      const float4 k0 = *(const float4*)(hs + ka * 64 + j0);
      const float4 k1 = *(const float4*)(hs + ka * 64 + j0 + 4);
      kn[0]=k0.x; kn[1]=k0.y; kn[2]=k0.z; kn[3]=k0.w;
      kn[4]=k1.x; kn[5]=k1.y; kn[6]=k1.z; kn[7]=k1.w;
      v0n = hs[vb * 64 + p0];
      v1n = hs[vb * 64 + p0 + 1];
    }
    {
      const int ni = (step < 3068) ? (step + 1) : 3068;
      nls_c = tab_g[2 * ni];         // uniform scalar loads, 1 step ahead
      c2i_c = tab_g[2 * ni + 1];
    }

    // ---- B: pred = w2 h + b2 ; d = (2/64)(pred - v)
    const v2f hh0 = mk2(h4.x, h4.y), hh1 = mk2(h4.z, h4.w);
    float q0 = 0.f, q1 = 0.f;
    q0 = fmaf(w2p[0].x, hh0.x, q0);  q1 = fmaf(w2p[2].x, hh0.x, q1);
    q0 = fmaf(w2p[0].y, hh0.y, q0);  q1 = fmaf(w2p[2].y, hh0.y, q1);
    q0 = fmaf(w2p[1].x, hh1.x, q0);  q1 = fmaf(w2p[3].x, hh1.x, q1);
    q0 = fmaf(w2p[1].y, hh1.y, q0);  q1 = fmaf(w2p[3].y, hh1.y, q1);
    q0 = dpp_add<0xB1>(q0);   q1 = dpp_add<0xB1>(q1);
    q0 = dpp_add<0x4E>(q0);   q1 = dpp_add<0x4E>(q1);
    q0 = dpp_add<0x141>(q0);  q1 = dpp_add<0x141>(q1);
    const float dd0 = 0.03125f * (q0 + b2v2.x - v0);
    const float dd1 = 0.03125f * (q1 + b2v2.y - v1);

    // ---- C: dp partials with OLD w2; xor8; store 4 partials/col
    {
      float dp[4];
      dp[0] = fmaf(w2p[2].x, dd1, w2p[0].x * dd0);
      dp[1] = fmaf(w2p[2].y, dd1, w2p[0].y * dd0);
      dp[2] = fmaf(w2p[3].x, dd1, w2p[1].x * dd0);
      dp[3] = fmaf(w2p[3].y, dd1, w2p[1].y * dd0);
#pragma unroll
      for (int ii = 0; ii < 4; ++ii) dp[ii] = dpp_add<0x128>(dp[ii]);  // xor8
      if (!(lane & 8)) {
        const int slot = wv * 4 + (lane >> 4);
        const int colb = (lane & 7) << 2;
        dhp[colb + 0][slot] = dp[0];
        dhp[colb + 1][slot] = dp[1];
        dhp[colb + 2][slot] = dp[2];
        dhp[colb + 3][slot] = dp[3];
      }
    }

    // ---- w2/b2 Adam (dp captured old w2; fills time to the barrier)
    adam_upd2(w2p[0], m1b2[0], m2b2[0], pk_mul(mk2(dd0, dd0), hh0), c2inv2, nls2);
    adam_upd2(w2p[1], m1b2[1], m2b2[1], pk_mul(mk2(dd0, dd0), hh1), c2inv2, nls2);
    adam_upd2(w2p[2], m1b2[2], m2b2[2], pk_mul(mk2(dd1, dd1), hh0), c2inv2, nls2);
    adam_upd2(w2p[3], m1b2[3], m2b2[3], pk_mul(mk2(dd1, dd1), hh1), c2inv2, nls2);
    adam_upd2(b2v2, m1d2, m2d2, mk2(dd0, dd1), c2inv2, nls2);
    __syncthreads();

    // ---- D: dhp reads FIRST after barrier (critical), exact xor-tree order
    {
      const float4 pA = *(const float4*)&dhp[i1][0];
      const float4 pB = *(const float4*)&dhp[i1][4];
      const float4 pC = *(const float4*)&dhp[i1][8];
      const float4 pD = *(const float4*)&dhp[i1][12];
      const float W0 = (pA.x + pA.y) + (pA.z + pA.w);
      const float W1 = (pB.x + pB.y) + (pB.z + pB.w);
      const float W2 = (pC.x + pC.y) + (pC.z + pC.w);
      const float W3 = (pD.x + pD.y) + (pD.z + pD.w);
      const float dhsum = (W0 + W1) + (W2 + W3);
      const float dh = (hv > 0.f) ? dhsum : 0.f;
      const v2f dh2 = mk2(dh, dh);
      adam_upd2(w1p[0], m1a2[0], m2a2[0],
                pk_mul(dh2, mk2(kk[0], kk[1])), c2inv2, nls2);
      adam_upd2(w1p[1], m1a2[1], m2a2[1],
                pk_mul(dh2, mk2(kk[2], kk[3])), c2inv2, nls2);
      adam_upd2(w1p[2], m1a2[2], m2a2[2],
                pk_mul(dh2, mk2(kk[4], kk[5])), c2inv2, nls2);
      adam_upd2(w1p[3], m1a2[3], m2a2[3],
                pk_mul(dh2, mk2(kk[6], kk[7])), c2inv2, nls2);
      adam_upd(b1v, m1c, m2c, dh, c2inv, nls);
    }

    // ---- A: h(step+1) with updated w1 and prefetched k
    {
#pragma unroll
      for (int jj = 0; jj < 8; ++jj) kk[jj] = kn[jj];
      v0 = v0n; v1 = v1n;
      float pa = 0.f;
      pa = fmaf(w1p[0].x, kk[0], pa);
      pa = fmaf(w1p[0].y, kk[1], pa);
      pa = fmaf(w1p[1].x, kk[2], pa);
      pa = fmaf(w1p[1].y, kk[3], pa);
      pa = fmaf(w1p[2].x, kk[4], pa);
      pa = fmaf(w1p[2].y, kk[5], pa);
      pa = fmaf(w1p[3].x, kk[6], pa);
      pa = fmaf(w1p[3].y, kk[7], pa);
      pa = dpp_add<0xB1>(pa);
      pa = dpp_add<0x4E>(pa);
      pa = dpp_add<0x141>(pa);
      hv = fmaxf(pa + b1v, 0.f);
      if (sub == 1) h_s[i1] = hv;
    }
    __syncthreads();
  }

  // ---- epilogue: ctx = w2 h_q + b2 (no relu on output layer)
  {
    const float4 h4 = *(const float4*)(&h_s[c0]);
    float q0 = 0.f, q1 = 0.f;
    q0 = fmaf(w2p[0].x, h4.x, q0); q1 = fmaf(w2p[2].x, h4.x, q1);
    q0 = fmaf(w2p[0].y, h4.y, q0); q1 = fmaf(w2p[2].y, h4.y, q1);
    q0 = fmaf(w2p[1].x, h4.z, q0); q1 = fmaf(w2p[3].x, h4.z, q1);
    q0 = fmaf(w2p[1].y, h4.w, q0); q1 = fmaf(w2p[3].y, h4.w, q1);
    q0 = dpp_add<0xB1>(q0);   q1 = dpp_add<0xB1>(q1);
    q0 = dpp_add<0x4E>(q0);   q1 = dpp_add<0x4E>(q1);
    q0 = dpp_add<0x141>(q0);  q1 = dpp_add<0x141>(q1);
    if (sub == 2) { ctx[p0] = q0 + b2v2.x; ctx[p0 + 1] = q1 + b2v2.y; }
  }
  __syncthreads();

  // ---- output projection: out[b][u] = out_b[u] + sum_p out_w[u][p]*ctx[p]
  if (t < 64) {
    float acc = outb[t];
    const float* wrow = outw + t * 64;
#pragma unroll 8
    for (int p = 0; p < 64; ++p) acc = fmaf(wrow[p], ctx[p], acc);
    out[(long long)b * 64 + t] = acc;
  }
}

extern "C" void kernel_launch(void* const* d_in, const int* in_sizes, int n_in,
                              void* d_out, int out_size, void* d_ws, size_t ws_size,
                              hipStream_t stream) {
  const int*   seq  = (const int*)  d_in[0];
  const float* emb  = (const float*)d_in[1];
  const float* ffw1 = (const float*)d_in[2];
  const float* ffb1 = (const float*)d_in[3];
  const float* ffw2 = (const float*)d_in[4];
  const float* ffb2 = (const float*)d_in[5];
  const float* lng  = (const float*)d_in[6];
  const float* lnb  = (const float*)d_in[7];
  const float* fc1w = (const float*)d_in[8];
  const float* fc1b = (const float*)d_in[9];
  const float* fc2w = (const float*)d_in[10];
  const float* fc2b = (const float*)d_in[11];
  const float* outw = (const float*)d_in[12];
  const float* outb = (const float*)d_in[13];
  float* out    = (float*)d_out;
  float* hs_tab = (float*)d_ws;            // 64*64 floats = 16 KB
  float* tab    = (float*)d_ws + 4096;     // 3069*2 floats

  prep_kernel<<<64, 128, 0, stream>>>(emb, ffw1, ffb1, ffw2, ffb2, lng, lnb, hs_tab);
  table_kernel<<<1, 64, 0, stream>>>(tab);
  scan_kernel<<<256, 256, 0, stream>>>(seq, hs_tab, tab, fc1w, fc1b, fc2w, fc2b,
                                       outw, outb, out);
}